// Round 1
// baseline (18812.540 us; speedup 1.0000x reference)
//
#include <hip/hip_runtime.h>
#include <math.h>

#define LMAXS 1024
#define NB 8
#define DIM 512
#define HEADS 8
#define DH 64
#define DEPTH 6
#define MLP 2048
#define NC 1000
#define PDIM 768

// per-image patch grid (w = W/16) and valid token counts L = h*w
__constant__ int c_w[8] = {32,24,32,24,28,32,16,20};
__constant__ int c_L[8] = {1024,768,896,576,560,512,384,640};

// ---- block-wide (256 thr) sum + sumsq reduction ----
__device__ __forceinline__ void reduce2_256(float& s, float& s2, float* red) {
  #pragma unroll
  for (int off = 32; off; off >>= 1) {
    s  += __shfl_xor(s, off);
    s2 += __shfl_xor(s2, off);
  }
  int wv = threadIdx.x >> 6;
  if ((threadIdx.x & 63) == 0) { red[wv*2] = s; red[wv*2+1] = s2; }
  __syncthreads();
  s  = red[0] + red[2] + red[4] + red[6];
  s2 = red[1] + red[3] + red[5] + red[7];
  __syncthreads();
}

// ---- patchify + LN(768) fused: one block per (b,l) token ----
__global__ __launch_bounds__(256) void pack_ln1_k(
    const float* __restrict__ images, const float* __restrict__ g,
    const float* __restrict__ bb, float* __restrict__ tok) {
  int bl = blockIdx.x;
  int b = bl >> 10, l = bl & (LMAXS-1);
  int wgrid = c_w[b], Lb = c_L[b];
  float* out = tok + (size_t)bl * PDIM;
  if (l >= Lb) {                    // padded token: row is exactly 0 (ln bias=0); masked later anyway
    for (int i = threadIdx.x; i < PDIM; i += 256) out[i] = 0.f;
    return;
  }
  __shared__ float vals[PDIM];
  __shared__ float red[8];
  int hp = l / wgrid, wp = l % wgrid;
  const float* base = images + (size_t)b*3*512*512 + (size_t)hp*16*512 + wp*16;
  float s = 0.f, s2 = 0.f;
  for (int i = threadIdx.x; i < PDIM; i += 256) {
    int c = i >> 8, r = (i >> 4) & 15, cc = i & 15;
    float v = base[(size_t)c*512*512 + r*512 + cc];
    vals[i] = v; s += v; s2 += v*v;
  }
  reduce2_256(s, s2, red);
  float mu = s * (1.f/PDIM);
  float rs = rsqrtf(fmaxf(s2*(1.f/PDIM) - mu*mu, 0.f) + 1e-5f);
  for (int i = threadIdx.x; i < PDIM; i += 256)
    out[i] = (vals[i]-mu)*rs*g[i] + bb[i];
}

// ---- generic fp32 GEMM: C[M,N] (+)= act(A[M,K] @ W[N,K]^T + bias) ----
// 128x128 tile, BK=16, 256 threads, 8x8 per thread. M%128==0, N%128==0, K%16==0.
template<int ACT, int ACC>
__global__ __launch_bounds__(256) void gemm_nt(
    const float* __restrict__ A, const float* __restrict__ W,
    const float* __restrict__ bias, float* __restrict__ C,
    int M, int N, int K) {
  __shared__ float As[16][128];
  __shared__ float Ws[16][128];
  int tid = threadIdx.x;
  int tx = tid & 15, ty = tid >> 4;
  int row0 = blockIdx.y * 128, col0 = blockIdx.x * 128;
  int lr = tid >> 1, lk = (tid & 1) * 8;
  const float* Ap = A + (size_t)(row0 + lr) * K + lk;
  const float* Wp = W + (size_t)(col0 + lr) * K + lk;
  float acc[8][8] = {};
  for (int k0 = 0; k0 < K; k0 += 16) {
    float4 a0 = *(const float4*)(Ap + k0);
    float4 a1 = *(const float4*)(Ap + k0 + 4);
    float4 w0 = *(const float4*)(Wp + k0);
    float4 w1 = *(const float4*)(Wp + k0 + 4);
    __syncthreads();
    As[lk+0][lr]=a0.x; As[lk+1][lr]=a0.y; As[lk+2][lr]=a0.z; As[lk+3][lr]=a0.w;
    As[lk+4][lr]=a1.x; As[lk+5][lr]=a1.y; As[lk+6][lr]=a1.z; As[lk+7][lr]=a1.w;
    Ws[lk+0][lr]=w0.x; Ws[lk+1][lr]=w0.y; Ws[lk+2][lr]=w0.z; Ws[lk+3][lr]=w0.w;
    Ws[lk+4][lr]=w1.x; Ws[lk+5][lr]=w1.y; Ws[lk+6][lr]=w1.z; Ws[lk+7][lr]=w1.w;
    __syncthreads();
    #pragma unroll
    for (int kk = 0; kk < 16; ++kk) {
      float a[8], bb[8];
      #pragma unroll
      for (int i = 0; i < 8; ++i) a[i] = As[kk][ty*8+i];
      #pragma unroll
      for (int j = 0; j < 8; ++j) bb[j] = Ws[kk][tx*8+j];
      #pragma unroll
      for (int i = 0; i < 8; ++i)
        #pragma unroll
        for (int j = 0; j < 8; ++j)
          acc[i][j] += a[i]*bb[j];
    }
  }
  #pragma unroll
  for (int i = 0; i < 8; ++i) {
    int r = row0 + ty*8 + i;
    float* cp = C + (size_t)r * N + col0 + tx*8;
    #pragma unroll
    for (int j = 0; j < 8; ++j) {
      float v = acc[i][j];
      if (bias) v += bias[col0 + tx*8 + j];
      if (ACT == 1) v = 0.5f*v*(1.f + erff(v*0.70710678118654752f));  // exact gelu
      if (ACC) cp[j] += v; else cp[j] = v;
    }
  }
}

// ---- row LayerNorm (width n, optional bias), X->Y ----
__global__ __launch_bounds__(256) void row_ln_k(
    const float* __restrict__ X, const float* __restrict__ g,
    const float* __restrict__ bb, float* __restrict__ Y, int n) {
  __shared__ float red[8];
  size_t base = (size_t)blockIdx.x * n;
  float s=0.f, s2=0.f;
  for (int i = threadIdx.x; i < n; i += 256) { float v = X[base+i]; s += v; s2 += v*v; }
  reduce2_256(s, s2, red);
  float mu = s/n, rs = rsqrtf(fmaxf(s2/n - mu*mu, 0.f) + 1e-5f);
  for (int i = threadIdx.x; i < n; i += 256) {
    float v = (X[base+i]-mu)*rs*g[i];
    if (bb) v += bb[i];
    Y[base+i] = v;
  }
}

// ---- LN2 + bias + pos embed + mask, in place on T ----
__global__ __launch_bounds__(256) void ln2_pos_mask_k(
    float* __restrict__ T, const float* __restrict__ g, const float* __restrict__ bb,
    const float* __restrict__ ph, const float* __restrict__ pw) {
  int bl = blockIdx.x;
  int b = bl >> 10, l = bl & (LMAXS-1);
  float* x = T + (size_t)bl * DIM;
  int Lb = c_L[b];
  if (l >= Lb) {
    for (int i = threadIdx.x; i < DIM; i += 256) x[i] = 0.f;
    return;
  }
  __shared__ float red[8];
  int wgrid = c_w[b];
  int hi = l / wgrid, wi = l % wgrid;
  float s=0.f, s2=0.f;
  for (int i = threadIdx.x; i < DIM; i += 256) { float v = x[i]; s+=v; s2+=v*v; }
  reduce2_256(s, s2, red);
  float mu = s*(1.f/DIM), rs = rsqrtf(fmaxf(s2*(1.f/DIM)-mu*mu, 0.f)+1e-5f);
  for (int i = threadIdx.x; i < DIM; i += 256)
    x[i] = (x[i]-mu)*rs*g[i] + bb[i] + ph[hi*DIM+i] + pw[wi*DIM+i];
}

// ---- per-head LN over DH=64, one wave per row, in place ----
__global__ __launch_bounds__(256) void head_ln_k(float* __restrict__ X, const float* __restrict__ g) {
  int row = blockIdx.x*4 + (threadIdx.x >> 6);
  int lane = threadIdx.x & 63;
  float* x = X + (size_t)row * DH;
  float v = x[lane];
  float s = v, s2 = v*v;
  #pragma unroll
  for (int off=32; off; off>>=1) { s += __shfl_xor(s,off); s2 += __shfl_xor(s2,off); }
  float mu = s*(1.f/DH), rs = rsqrtf(fmaxf(s2*(1.f/DH)-mu*mu, 0.f)+1e-5f);
  x[lane] = (v-mu)*rs*g[lane];
}

// ---- fused flash attention: 1 wave = 8 queries, lane = key / dim ----
__global__ __launch_bounds__(256) void attn_k(
    const float* __restrict__ Q, const float* __restrict__ Kb,
    const float* __restrict__ Vb, float* __restrict__ O) {
  __shared__ float q_s[4][8][64];
  __shared__ float p_s[4][8][64];
  int bh = blockIdx.x;
  int b = bh >> 3, h = bh & 7;
  int wv = threadIdx.x >> 6, lane = threadIdx.x & 63;
  int qbase = blockIdx.y * 32 + wv * 8;
  int Lb = c_L[b];
  size_t hb = (size_t)b * LMAXS * DIM + h * DH;
  #pragma unroll
  for (int qi = 0; qi < 8; ++qi)
    q_s[wv][qi][lane] = Q[hb + (size_t)(qbase+qi)*DIM + lane];
  float o[8] = {}, lsum[8] = {}, m[8];
  #pragma unroll
  for (int qi = 0; qi < 8; ++qi) m[qi] = -INFINITY;
  for (int kc = 0; kc < LMAXS; kc += 64) {
    int kidx = kc + lane;
    const float4* kp = (const float4*)(Kb + hb + (size_t)kidx*DIM);
    float s[8] = {};
    #pragma unroll
    for (int dd = 0; dd < 16; ++dd) {
      float4 kv = kp[dd];
      #pragma unroll
      for (int qi = 0; qi < 8; ++qi) {
        float4 qv = *(const float4*)&q_s[wv][qi][dd*4];
        s[qi] += kv.x*qv.x + kv.y*qv.y + kv.z*qv.z + kv.w*qv.w;
      }
    }
    float madd = (kidx < Lb) ? 0.f : -1e9f;   // valid keys are a prefix -> m finite before masked chunks
    #pragma unroll
    for (int qi = 0; qi < 8; ++qi) {
      float sv = s[qi]*0.125f + madd;
      float tm = sv;
      #pragma unroll
      for (int off=32; off; off>>=1) tm = fmaxf(tm, __shfl_xor(tm, off));
      float mn = fmaxf(m[qi], tm);
      float al = __expf(m[qi] - mn);
      float p = __expf(sv - mn);
      float ps = p;
      #pragma unroll
      for (int off=32; off; off>>=1) ps += __shfl_xor(ps, off);
      lsum[qi] = lsum[qi]*al + ps;
      o[qi] *= al;
      m[qi] = mn;
      p_s[wv][qi][lane] = p;                   // wave-private, wave-synchronous LDS
    }
    const float* vb = Vb + hb + (size_t)kc*DIM + lane;
    #pragma unroll 8
    for (int k = 0; k < 64; ++k) {
      float vvv = vb[(size_t)k*DIM];
      #pragma unroll
      for (int qi = 0; qi < 8; ++qi)
        o[qi] += p_s[wv][qi][k] * vvv;
    }
  }
  #pragma unroll
  for (int qi = 0; qi < 8; ++qi)
    O[hb + (size_t)(qbase+qi)*DIM + lane] = o[qi] / lsum[qi];
}

// ---- pool query: LN(pool_q) @ pool_wq^T then per-head LN (same for all b) ----
__global__ __launch_bounds__(256) void pool_prep_k(
    const float* __restrict__ pq, const float* __restrict__ pln,
    const float* __restrict__ pwq, const float* __restrict__ pqn,
    float* __restrict__ qout) {
  __shared__ float qln[DIM];
  __shared__ float qp[DIM];
  __shared__ float red[8];
  __shared__ float hstat[16];
  int tid = threadIdx.x;
  float s=0.f, s2=0.f;
  for (int i=tid;i<DIM;i+=256){ float v=pq[i]; s+=v; s2+=v*v; }
  reduce2_256(s, s2, red);
  float mu=s*(1.f/DIM), rs=rsqrtf(fmaxf(s2*(1.f/DIM)-mu*mu,0.f)+1e-5f);
  for (int i=tid;i<DIM;i+=256) qln[i]=(pq[i]-mu)*rs*pln[i];
  __syncthreads();
  for (int n=tid;n<DIM;n+=256) {
    float a=0.f;
    const float* wr = pwq + (size_t)n*DIM;
    for (int k=0;k<DIM;++k) a += qln[k]*wr[k];
    qp[n]=a;
  }
  __syncthreads();
  if (tid < 8) {
    float hs=0.f, hs2=0.f;
    for (int i=0;i<64;++i){ float v=qp[tid*64+i]; hs+=v; hs2+=v*v; }
    float hmu=hs*(1.f/64), hv=hs2*(1.f/64)-hmu*hmu;
    hstat[tid*2]=hmu; hstat[tid*2+1]=rsqrtf(fmaxf(hv,0.f)+1e-5f);
  }
  __syncthreads();
  for (int i=tid;i<DIM;i+=256) {
    int hh=i>>6;
    qout[i]=(qp[i]-hstat[hh*2])*hstat[hh*2+1]*pqn[i&63];
  }
}

// ---- pooling cross-attention: 1 query per (b,h), full softmax in LDS ----
__global__ __launch_bounds__(256) void pool_attn_k(
    const float* __restrict__ qpool, const float* __restrict__ Kb,
    const float* __restrict__ Vb, float* __restrict__ O) {
  __shared__ float ss[LMAXS];
  __shared__ float qh[DH];
  __shared__ float red[4];
  __shared__ float part[4][DH];
  int bh = blockIdx.x, b = bh>>3, h = bh&7;
  int tid = threadIdx.x;
  int Lb = c_L[b];
  if (tid < DH) qh[tid] = qpool[h*DH + tid];
  __syncthreads();
  size_t hb = (size_t)b*LMAXS*DIM + h*DH;
  for (int k = tid; k < LMAXS; k += 256) {
    const float4* kp = (const float4*)(Kb + hb + (size_t)k*DIM);
    float a = 0.f;
    #pragma unroll
    for (int dd=0; dd<16; ++dd) {
      float4 kv = kp[dd];
      a += kv.x*qh[dd*4] + kv.y*qh[dd*4+1] + kv.z*qh[dd*4+2] + kv.w*qh[dd*4+3];
    }
    ss[k] = a*0.125f + ((k < Lb) ? 0.f : -1e9f);
  }
  __syncthreads();
  float mx = -INFINITY;
  for (int k=tid;k<LMAXS;k+=256) mx = fmaxf(mx, ss[k]);
  #pragma unroll
  for (int off=32; off; off>>=1) mx = fmaxf(mx, __shfl_xor(mx,off));
  if ((tid&63)==0) red[tid>>6] = mx;
  __syncthreads();
  mx = fmaxf(fmaxf(red[0],red[1]), fmaxf(red[2],red[3]));
  __syncthreads();
  float sum = 0.f;
  for (int k=tid;k<LMAXS;k+=256) { float p = __expf(ss[k]-mx); ss[k]=p; sum += p; }
  #pragma unroll
  for (int off=32; off; off>>=1) sum += __shfl_xor(sum,off);
  if ((tid&63)==0) red[tid>>6] = sum;
  __syncthreads();
  sum = red[0]+red[1]+red[2]+red[3];
  int d = tid & 63, c = tid >> 6;
  float a = 0.f;
  const float* vb = Vb + hb + d;
  for (int k = c*256; k < c*256+256; ++k) a += ss[k]*vb[(size_t)k*DIM];
  part[c][d] = a;
  __syncthreads();
  if (tid < DH)
    O[(size_t)b*DIM + h*DH + tid] = (part[0][tid]+part[1][tid]+part[2][tid]+part[3][tid]) / sum;
}

// ---- tiny projection Y[8,512] = X[8,512] @ W[512,512]^T ----
__global__ __launch_bounds__(256) void proj512_k(
    const float* __restrict__ X, const float* __restrict__ W, float* __restrict__ Y) {
  __shared__ float xr[DIM];
  int b = blockIdx.x, tid = threadIdx.x;
  for (int i=tid;i<DIM;i+=256) xr[i] = X[(size_t)b*DIM+i];
  __syncthreads();
  for (int n=tid;n<DIM;n+=256) {
    const float4* wr = (const float4*)(W + (size_t)n*DIM);
    float a=0.f;
    for (int k=0;k<DIM/4;++k) { float4 w4 = wr[k]; a += w4.x*xr[k*4]+w4.y*xr[k*4+1]+w4.z*xr[k*4+2]+w4.w*xr[k*4+3]; }
    Y[(size_t)b*DIM+n]=a;
  }
}

// ---- final LN + classifier head: out[8,1000] ----
__global__ __launch_bounds__(256) void head_out_k(
    const float* __restrict__ X, const float* __restrict__ g,
    const float* __restrict__ W, float* __restrict__ out) {
  __shared__ float xr[DIM];
  __shared__ float red[8];
  int b = blockIdx.x, tid = threadIdx.x;
  float s=0.f, s2=0.f;
  for (int i=tid;i<DIM;i+=256){ float v=X[(size_t)b*DIM+i]; s+=v; s2+=v*v; }
  reduce2_256(s, s2, red);
  float mu=s*(1.f/DIM), rs=rsqrtf(fmaxf(s2*(1.f/DIM)-mu*mu,0.f)+1e-5f);
  for (int i=tid;i<DIM;i+=256) xr[i]=(X[(size_t)b*DIM+i]-mu)*rs*g[i];
  __syncthreads();
  for (int n=tid;n<NC;n+=256) {
    const float4* wr = (const float4*)(W + (size_t)n*DIM);
    float a=0.f;
    for (int k=0;k<DIM/4;++k){ float4 w4=wr[k]; a += w4.x*xr[k*4]+w4.y*xr[k*4+1]+w4.z*xr[k*4+2]+w4.w*xr[k*4+3]; }
    out[(size_t)b*NC+n]=a;
  }
}

extern "C" void kernel_launch(void* const* d_in, const int* in_sizes, int n_in,
                              void* d_out, int out_size, void* d_ws, size_t ws_size,
                              hipStream_t stream) {
  const float* images  = (const float*)d_in[0];
  const float* pe_ln1_w= (const float*)d_in[1];
  const float* pe_ln1_b= (const float*)d_in[2];
  const float* pe_w    = (const float*)d_in[3];
  const float* pe_b    = (const float*)d_in[4];
  const float* pe_ln2_w= (const float*)d_in[5];
  const float* pe_ln2_b= (const float*)d_in[6];
  const float* pos_h   = (const float*)d_in[7];
  const float* pos_w   = (const float*)d_in[8];
  const float* attn_ln = (const float*)d_in[9];
  const float* wq      = (const float*)d_in[10];
  const float* wk      = (const float*)d_in[11];
  const float* wvp     = (const float*)d_in[12];
  const float* qn      = (const float*)d_in[13];
  const float* kn      = (const float*)d_in[14];
  const float* wo      = (const float*)d_in[15];
  const float* ff_ln   = (const float*)d_in[16];
  const float* ff_w1   = (const float*)d_in[17];
  const float* ff_b1   = (const float*)d_in[18];
  const float* ff_w2   = (const float*)d_in[19];
  const float* ff_b2   = (const float*)d_in[20];
  const float* final_ln= (const float*)d_in[21];
  const float* pool_q  = (const float*)d_in[22];
  const float* pool_ln = (const float*)d_in[23];
  const float* pool_wq = (const float*)d_in[24];
  const float* pool_wk = (const float*)d_in[25];
  const float* pool_wv = (const float*)d_in[26];
  const float* pool_qn = (const float*)d_in[27];
  const float* pool_kn = (const float*)d_in[28];
  const float* pool_wo = (const float*)d_in[29];
  const float* head_ln = (const float*)d_in[30];
  const float* head_w  = (const float*)d_in[31];

  const size_t NTOK = (size_t)NB * LMAXS;   // 8192 rows
  float* ws = (float*)d_ws;
  // FFH region (8192*2048) doubles as: TOK (patch tokens, dead after embed) and attention output
  float* FFH   = ws;
  float* TOK   = ws;
  float* ATTO  = ws;
  float* T     = ws + NTOK*MLP;             // +16.7M floats
  float* XN    = T   + NTOK*DIM;
  float* Qb    = XN  + NTOK*DIM;
  float* Kbuf  = Qb  + NTOK*DIM;
  float* Vbuf  = Kbuf+ NTOK*DIM;
  float* QPOOL = Vbuf+ NTOK*DIM;            // 512
  float* POOLO = QPOOL + DIM;               // 8*512
  float* POOLED= POOLO + NB*DIM;            // 8*512
  (void)ws_size; (void)in_sizes; (void)n_in; (void)out_size;

  // ---- patch embed ----
  pack_ln1_k<<<NTOK, 256, 0, stream>>>(images, pe_ln1_w, pe_ln1_b, TOK);
  gemm_nt<0,0><<<dim3(DIM/128, NTOK/128), 256, 0, stream>>>(TOK, pe_w, pe_b, T, (int)NTOK, DIM, PDIM);
  ln2_pos_mask_k<<<NTOK, 256, 0, stream>>>(T, pe_ln2_w, pe_ln2_b, pos_h, pos_w);

  // ---- transformer layers ----
  for (int l = 0; l < DEPTH; ++l) {
    row_ln_k<<<NTOK, 256, 0, stream>>>(T, attn_ln + l*DIM, nullptr, XN, DIM);
    gemm_nt<0,0><<<dim3(4, 64), 256, 0, stream>>>(XN, wq  + (size_t)l*DIM*DIM, nullptr, Qb,   (int)NTOK, DIM, DIM);
    gemm_nt<0,0><<<dim3(4, 64), 256, 0, stream>>>(XN, wk  + (size_t)l*DIM*DIM, nullptr, Kbuf, (int)NTOK, DIM, DIM);
    gemm_nt<0,0><<<dim3(4, 64), 256, 0, stream>>>(XN, wvp + (size_t)l*DIM*DIM, nullptr, Vbuf, (int)NTOK, DIM, DIM);
    head_ln_k<<<NTOK*HEADS/4, 256, 0, stream>>>(Qb,   qn + l*DH);
    head_ln_k<<<NTOK*HEADS/4, 256, 0, stream>>>(Kbuf, kn + l*DH);
    attn_k<<<dim3(NB*HEADS, LMAXS/32), 256, 0, stream>>>(Qb, Kbuf, Vbuf, ATTO);
    gemm_nt<0,1><<<dim3(4, 64), 256, 0, stream>>>(ATTO, wo + (size_t)l*DIM*DIM, nullptr, T, (int)NTOK, DIM, DIM);
    row_ln_k<<<NTOK, 256, 0, stream>>>(T, ff_ln + l*DIM, nullptr, XN, DIM);
    gemm_nt<1,0><<<dim3(MLP/128, 64), 256, 0, stream>>>(XN, ff_w1 + (size_t)l*MLP*DIM, ff_b1 + l*MLP, FFH, (int)NTOK, MLP, DIM);
    gemm_nt<0,1><<<dim3(4, 64), 256, 0, stream>>>(FFH, ff_w2 + (size_t)l*DIM*MLP, ff_b2 + l*DIM, T, (int)NTOK, DIM, MLP);
  }

  // ---- pooling head ----
  row_ln_k<<<NTOK, 256, 0, stream>>>(T, final_ln, nullptr, XN, DIM);
  pool_prep_k<<<1, 256, 0, stream>>>(pool_q, pool_ln, pool_wq, pool_qn, QPOOL);
  gemm_nt<0,0><<<dim3(4, 64), 256, 0, stream>>>(XN, pool_wk, nullptr, Kbuf, (int)NTOK, DIM, DIM);
  gemm_nt<0,0><<<dim3(4, 64), 256, 0, stream>>>(XN, pool_wv, nullptr, Vbuf, (int)NTOK, DIM, DIM);
  head_ln_k<<<NTOK*HEADS/4, 256, 0, stream>>>(Kbuf, pool_kn);
  pool_attn_k<<<NB*HEADS, 256, 0, stream>>>(QPOOL, Kbuf, Vbuf, POOLO);
  proj512_k<<<NB, 256, 0, stream>>>(POOLO, pool_wo, POOLED);
  head_out_k<<<NB, 256, 0, stream>>>(POOLED, head_ln, head_w, (float*)d_out);
}

// Round 2
// 5707.065 us; speedup vs baseline: 3.2964x; 3.2964x over previous
//
#include <hip/hip_runtime.h>
#include <math.h>

#define LMAXS 1024
#define NB 8
#define DIM 512
#define HEADS 8
#define DH 64
#define DEPTH 6
#define MLP 2048
#define NC 1000
#define PDIM 768
#define MPACK 5376   // 5360 valid rows padded to 42*128
#define MVALID 5360

typedef __attribute__((ext_vector_type(8))) short short8;
typedef __attribute__((ext_vector_type(4))) float floatx4;
typedef unsigned short ushort;

// per-image patch grid width, valid token count L, packed row offset
__constant__ int c_w[8]   = {32,24,32,24,28,32,16,20};
__constant__ int c_L[8]   = {1024,768,896,576,560,512,384,640};
__constant__ int c_off[9] = {0,1024,1792,2688,3264,3824,4336,4720,5360};

__device__ __forceinline__ int row2img(int r) {
  int b = 0;
  #pragma unroll
  for (int i = 1; i < 8; ++i) if (r >= c_off[i]) b = i;
  return b;
}

__device__ __forceinline__ ushort f2bf(float x) {
  unsigned int u = __float_as_uint(x);
  u += 0x7fff + ((u >> 16) & 1);          // RNE
  return (ushort)(u >> 16);
}

// ---- block-wide (256 thr) sum + sumsq reduction ----
__device__ __forceinline__ void reduce2_256(float& s, float& s2, float* red) {
  #pragma unroll
  for (int off = 32; off; off >>= 1) {
    s  += __shfl_xor(s, off);
    s2 += __shfl_xor(s2, off);
  }
  int wv = threadIdx.x >> 6;
  if ((threadIdx.x & 63) == 0) { red[wv*2] = s; red[wv*2+1] = s2; }
  __syncthreads();
  s  = red[0] + red[2] + red[4] + red[6];
  s2 = red[1] + red[3] + red[5] + red[7];
  __syncthreads();
}

// ---- patchify + LN(768), packed rows: one block per valid token ----
__global__ __launch_bounds__(256) void pack_ln1_k(
    const float* __restrict__ images, const float* __restrict__ g,
    const float* __restrict__ bb, float* __restrict__ tok) {
  int r = blockIdx.x;
  float* out = tok + (size_t)r * PDIM;
  if (r >= MVALID) {                       // alignment tail: keep GEMM input finite
    for (int i = threadIdx.x; i < PDIM; i += 256) out[i] = 0.f;
    return;
  }
  int b = row2img(r), l = r - c_off[b];
  int wgrid = c_w[b];
  __shared__ float vals[PDIM];
  __shared__ float red[8];
  int hp = l / wgrid, wp = l % wgrid;
  const float* base = images + (size_t)b*3*512*512 + (size_t)hp*16*512 + wp*16;
  float s = 0.f, s2 = 0.f;
  for (int i = threadIdx.x; i < PDIM; i += 256) {
    int c = i >> 8, rr = (i >> 4) & 15, cc = i & 15;
    float v = base[(size_t)c*512*512 + rr*512 + cc];
    vals[i] = v; s += v; s2 += v*v;
  }
  reduce2_256(s, s2, red);
  float mu = s * (1.f/PDIM);
  float rs = rsqrtf(fmaxf(s2*(1.f/PDIM) - mu*mu, 0.f) + 1e-5f);
  for (int i = threadIdx.x; i < PDIM; i += 256)
    out[i] = (vals[i]-mu)*rs*g[i] + bb[i];
}

// ---- generic fp32 GEMM: C[M,N] (+)= act(A[M,K] @ W[N,K]^T + bias) ----
template<int ACT, int ACC>
__global__ __launch_bounds__(256) void gemm_nt(
    const float* __restrict__ A, const float* __restrict__ W,
    const float* __restrict__ bias, float* __restrict__ C,
    int M, int N, int K) {
  __shared__ float As[16][128];
  __shared__ float Ws[16][128];
  int tid = threadIdx.x;
  int tx = tid & 15, ty = tid >> 4;
  int row0 = blockIdx.y * 128, col0 = blockIdx.x * 128;
  int lr = tid >> 1, lk = (tid & 1) * 8;
  const float* Ap = A + (size_t)(row0 + lr) * K + lk;
  const float* Wp = W + (size_t)(col0 + lr) * K + lk;
  float acc[8][8] = {};
  for (int k0 = 0; k0 < K; k0 += 16) {
    float4 a0 = *(const float4*)(Ap + k0);
    float4 a1 = *(const float4*)(Ap + k0 + 4);
    float4 w0 = *(const float4*)(Wp + k0);
    float4 w1 = *(const float4*)(Wp + k0 + 4);
    __syncthreads();
    As[lk+0][lr]=a0.x; As[lk+1][lr]=a0.y; As[lk+2][lr]=a0.z; As[lk+3][lr]=a0.w;
    As[lk+4][lr]=a1.x; As[lk+5][lr]=a1.y; As[lk+6][lr]=a1.z; As[lk+7][lr]=a1.w;
    Ws[lk+0][lr]=w0.x; Ws[lk+1][lr]=w0.y; Ws[lk+2][lr]=w0.z; Ws[lk+3][lr]=w0.w;
    Ws[lk+4][lr]=w1.x; Ws[lk+5][lr]=w1.y; Ws[lk+6][lr]=w1.z; Ws[lk+7][lr]=w1.w;
    __syncthreads();
    #pragma unroll
    for (int kk = 0; kk < 16; ++kk) {
      float a[8], bb[8];
      #pragma unroll
      for (int i = 0; i < 8; ++i) a[i] = As[kk][ty*8+i];
      #pragma unroll
      for (int j = 0; j < 8; ++j) bb[j] = Ws[kk][tx*8+j];
      #pragma unroll
      for (int i = 0; i < 8; ++i)
        #pragma unroll
        for (int j = 0; j < 8; ++j)
          acc[i][j] += a[i]*bb[j];
    }
  }
  #pragma unroll
  for (int i = 0; i < 8; ++i) {
    int r = row0 + ty*8 + i;
    float* cp = C + (size_t)r * N + col0 + tx*8;
    #pragma unroll
    for (int j = 0; j < 8; ++j) {
      float v = acc[i][j];
      if (bias) v += bias[col0 + tx*8 + j];
      if (ACT == 1) v = 0.5f*v*(1.f + erff(v*0.70710678118654752f));
      if (ACC) cp[j] += v; else cp[j] = v;
    }
  }
}

// ---- row LayerNorm (width n), X->Y ----
__global__ __launch_bounds__(256) void row_ln_k(
    const float* __restrict__ X, const float* __restrict__ g,
    float* __restrict__ Y, int n) {
  __shared__ float red[8];
  size_t base = (size_t)blockIdx.x * n;
  float s=0.f, s2=0.f;
  for (int i = threadIdx.x; i < n; i += 256) { float v = X[base+i]; s += v; s2 += v*v; }
  reduce2_256(s, s2, red);
  float mu = s/n, rs = rsqrtf(fmaxf(s2/n - mu*mu, 0.f) + 1e-5f);
  for (int i = threadIdx.x; i < n; i += 256)
    Y[base+i] = (X[base+i]-mu)*rs*g[i];
}

// ---- LN2 + bias + pos embed, packed, in place on T ----
__global__ __launch_bounds__(256) void ln2_pos_k(
    float* __restrict__ T, const float* __restrict__ g, const float* __restrict__ bb,
    const float* __restrict__ ph, const float* __restrict__ pw) {
  int r = blockIdx.x;
  float* x = T + (size_t)r * DIM;
  if (r >= MVALID) {
    for (int i = threadIdx.x; i < DIM; i += 256) x[i] = 0.f;
    return;
  }
  int b = row2img(r), l = r - c_off[b];
  __shared__ float red[8];
  int wgrid = c_w[b];
  int hi = l / wgrid, wi = l % wgrid;
  float s=0.f, s2=0.f;
  for (int i = threadIdx.x; i < DIM; i += 256) { float v = x[i]; s+=v; s2+=v*v; }
  reduce2_256(s, s2, red);
  float mu = s*(1.f/DIM), rs = rsqrtf(fmaxf(s2*(1.f/DIM)-mu*mu, 0.f)+1e-5f);
  for (int i = threadIdx.x; i < DIM; i += 256)
    x[i] = (x[i]-mu)*rs*g[i] + bb[i] + ph[hi*DIM+i] + pw[wi*DIM+i];
}

// ---- per-head LN over DH=64, one wave per row (for pool K) ----
__global__ __launch_bounds__(256) void head_ln_k(float* __restrict__ X, const float* __restrict__ g) {
  int row = blockIdx.x*4 + (threadIdx.x >> 6);
  int lane = threadIdx.x & 63;
  float* x = X + (size_t)row * DH;
  float v = x[lane];
  float s = v, s2 = v*v;
  #pragma unroll
  for (int off=32; off; off>>=1) { s += __shfl_xor(s,off); s2 += __shfl_xor(s2,off); }
  float mu = s*(1.f/DH), rs = rsqrtf(fmaxf(s2*(1.f/DH)-mu*mu, 0.f)+1e-5f);
  x[lane] = (v-mu)*rs*g[lane];
}

// ---- QKV split to per-head bf16 [b,h,l,64] with fused head-LN on Q,K ----
__global__ __launch_bounds__(512) void split_ln_k(
    const float* __restrict__ Qb, const float* __restrict__ Kb, const float* __restrict__ Vb,
    const float* __restrict__ qn, const float* __restrict__ kn,
    ushort* __restrict__ Qh, ushort* __restrict__ Kh, ushort* __restrict__ Vh) {
  int r = blockIdx.x;                  // 0..MVALID-1
  int h = threadIdx.x >> 6, lane = threadIdx.x & 63;
  int b = row2img(r), l = r - c_off[b];
  size_t src = (size_t)r*DIM + h*DH + lane;
  size_t dst = ((size_t)(b*8+h)*LMAXS + l)*DH + lane;
  float v, s, s2, mu, rs;

  v = Qb[src]; s = v; s2 = v*v;
  #pragma unroll
  for (int off=32; off; off>>=1) { s += __shfl_xor(s,off); s2 += __shfl_xor(s2,off); }
  mu = s*(1.f/DH); rs = rsqrtf(fmaxf(s2*(1.f/DH)-mu*mu,0.f)+1e-5f);
  Qh[dst] = f2bf((v-mu)*rs*qn[lane]);

  v = Kb[src]; s = v; s2 = v*v;
  #pragma unroll
  for (int off=32; off; off>>=1) { s += __shfl_xor(s,off); s2 += __shfl_xor(s2,off); }
  mu = s*(1.f/DH); rs = rsqrtf(fmaxf(s2*(1.f/DH)-mu*mu,0.f)+1e-5f);
  Kh[dst] = f2bf((v-mu)*rs*kn[lane]);

  Vh[dst] = f2bf(Vb[src]);
}

// ---- bf16 MFMA flash attention ----
// grid.x = b*8+h (64), grid.y = q-tile of 64 (16). Block 256 = 4 waves, wave = 16 queries.
// LDS: K chunk [64k][72d] bf16, V^T chunk [64d][72k] bf16, P per-wave [16q][72k] bf16.
__global__ __launch_bounds__(256) void attn_mfma_k(
    const ushort* __restrict__ Qh, const ushort* __restrict__ Kh,
    const ushort* __restrict__ Vh, float* __restrict__ O) {
  int bh = blockIdx.x, b = bh >> 3, h = bh & 7;
  int Lb = c_L[b];
  int qt = blockIdx.y;
  if (qt * 64 >= Lb) return;
  __shared__ ushort Ks[64][72];
  __shared__ ushort Vt[64][72];
  __shared__ ushort Pb[4][16][72];
  int tid = threadIdx.x, wv = tid >> 6, lane = tid & 63;
  int quad = lane >> 4, l15 = lane & 15;
  int q0 = qt*64 + wv*16;
  bool active = q0 < Lb;               // L % 16 == 0 for all images: no partial wave tiles
  const ushort* qhb = Qh + (size_t)bh * LMAXS * DH;
  const ushort* khb = Kh + (size_t)bh * LMAXS * DH;
  const ushort* vhb = Vh + (size_t)bh * LMAXS * DH;
  short8 aq0 = {}, aq1 = {};
  if (active) {
    const ushort* qp = qhb + (size_t)(q0 + l15) * DH;
    aq0 = *(const short8*)(qp + quad*8);
    aq1 = *(const short8*)(qp + 32 + quad*8);
  }
  float mrow[4] = {-1e30f,-1e30f,-1e30f,-1e30f};
  float lrow[4] = {0.f,0.f,0.f,0.f};
  floatx4 o[4] = {};
  int krow = tid >> 2, dcol = (tid & 3) * 16;   // staging: 4 threads per key row
  for (int kc = 0; kc < Lb; kc += 64) {
    __syncthreads();
    const ushort* kr = khb + (size_t)(kc + krow) * DH + dcol;
    *(short8*)&Ks[krow][dcol]   = *(const short8*)kr;
    *(short8*)&Ks[krow][dcol+8] = *(const short8*)(kr + 8);
    const ushort* vr = vhb + (size_t)(kc + krow) * DH + dcol;
    short8 v0 = *(const short8*)vr;
    short8 v1 = *(const short8*)(vr + 8);
    #pragma unroll
    for (int j = 0; j < 8; ++j) Vt[dcol+j][krow]   = (ushort)v0[j];
    #pragma unroll
    for (int j = 0; j < 8; ++j) Vt[dcol+8+j][krow] = (ushort)v1[j];
    __syncthreads();
    if (!active) continue;
    floatx4 sv[4];
    #pragma unroll
    for (int kb = 0; kb < 4; ++kb) {
      floatx4 s = {};
      s = __builtin_amdgcn_mfma_f32_16x16x32_bf16(aq0, *(const short8*)&Ks[kb*16+l15][quad*8], s, 0,0,0);
      s = __builtin_amdgcn_mfma_f32_16x16x32_bf16(aq1, *(const short8*)&Ks[kb*16+l15][32+quad*8], s, 0,0,0);
      sv[kb] = s;
    }
    bool tail = (kc + 64 > Lb);
    float rmax[4] = {-1e30f,-1e30f,-1e30f,-1e30f};
    #pragma unroll
    for (int kb = 0; kb < 4; ++kb)
      #pragma unroll
      for (int reg = 0; reg < 4; ++reg) {
        float x = sv[kb][reg] * 0.125f;
        if (tail && (kc + kb*16 + l15 >= Lb)) x = -1e9f;
        sv[kb][reg] = x;
        rmax[reg] = fmaxf(rmax[reg], x);
      }
    #pragma unroll
    for (int reg = 0; reg < 4; ++reg) {
      #pragma unroll
      for (int off = 1; off < 16; off <<= 1) rmax[reg] = fmaxf(rmax[reg], __shfl_xor(rmax[reg], off));
    }
    float alpha[4], rsum[4] = {0.f,0.f,0.f,0.f};
    #pragma unroll
    for (int reg = 0; reg < 4; ++reg) {
      float mn = fmaxf(mrow[reg], rmax[reg]);
      alpha[reg] = __expf(mrow[reg] - mn);
      mrow[reg] = mn;
    }
    #pragma unroll
    for (int kb = 0; kb < 4; ++kb)
      #pragma unroll
      for (int reg = 0; reg < 4; ++reg) {
        float p = __expf(sv[kb][reg] - mrow[reg]);
        rsum[reg] += p;
        Pb[wv][quad*4+reg][kb*16+l15] = f2bf(p);
      }
    #pragma unroll
    for (int reg = 0; reg < 4; ++reg) {
      #pragma unroll
      for (int off = 1; off < 16; off <<= 1) rsum[reg] += __shfl_xor(rsum[reg], off);
      lrow[reg] = lrow[reg]*alpha[reg] + rsum[reg];
    }
    #pragma unroll
    for (int nb = 0; nb < 4; ++nb)
      #pragma unroll
      for (int reg = 0; reg < 4; ++reg) o[nb][reg] *= alpha[reg];
    short8 a0 = *(const short8*)&Pb[wv][l15][quad*8];
    short8 a1 = *(const short8*)&Pb[wv][l15][32+quad*8];
    #pragma unroll
    for (int nb = 0; nb < 4; ++nb) {
      o[nb] = __builtin_amdgcn_mfma_f32_16x16x32_bf16(a0, *(const short8*)&Vt[nb*16+l15][quad*8], o[nb], 0,0,0);
      o[nb] = __builtin_amdgcn_mfma_f32_16x16x32_bf16(a1, *(const short8*)&Vt[nb*16+l15][32+quad*8], o[nb], 0,0,0);
    }
  }
  if (active) {
    int rbase = c_off[b] + q0 + quad*4;
    #pragma unroll
    for (int nb = 0; nb < 4; ++nb)
      #pragma unroll
      for (int reg = 0; reg < 4; ++reg)
        O[(size_t)(rbase+reg)*DIM + h*DH + nb*16 + l15] = o[nb][reg] / lrow[reg];
  }
}

// ---- pool query: LN(pool_q) @ pool_wq^T then per-head LN ----
__global__ __launch_bounds__(256) void pool_prep_k(
    const float* __restrict__ pq, const float* __restrict__ pln,
    const float* __restrict__ pwq, const float* __restrict__ pqn,
    float* __restrict__ qout) {
  __shared__ float qln[DIM];
  __shared__ float qp[DIM];
  __shared__ float red[8];
  __shared__ float hstat[16];
  int tid = threadIdx.x;
  float s=0.f, s2=0.f;
  for (int i=tid;i<DIM;i+=256){ float v=pq[i]; s+=v; s2+=v*v; }
  reduce2_256(s, s2, red);
  float mu=s*(1.f/DIM), rs=rsqrtf(fmaxf(s2*(1.f/DIM)-mu*mu,0.f)+1e-5f);
  for (int i=tid;i<DIM;i+=256) qln[i]=(pq[i]-mu)*rs*pln[i];
  __syncthreads();
  for (int n=tid;n<DIM;n+=256) {
    const float4* wr = (const float4*)(pwq + (size_t)n*DIM);
    float a=0.f;
    for (int k=0;k<DIM/4;++k) {
      float4 w4 = wr[k];
      float4 q4 = *(const float4*)&qln[k*4];
      a += w4.x*q4.x + w4.y*q4.y + w4.z*q4.z + w4.w*q4.w;
    }
    qp[n]=a;
  }
  __syncthreads();
  if (tid < 8) {
    float hs=0.f, hs2=0.f;
    for (int i=0;i<64;++i){ float v=qp[tid*64+i]; hs+=v; hs2+=v*v; }
    float hmu=hs*(1.f/64), hv=hs2*(1.f/64)-hmu*hmu;
    hstat[tid*2]=hmu; hstat[tid*2+1]=rsqrtf(fmaxf(hv,0.f)+1e-5f);
  }
  __syncthreads();
  for (int i=tid;i<DIM;i+=256) {
    int hh=i>>6;
    qout[i]=(qp[i]-hstat[hh*2])*hstat[hh*2+1]*pqn[i&63];
  }
}

// ---- pooling cross-attention over packed keys ----
__global__ __launch_bounds__(256) void pool_attn_k(
    const float* __restrict__ qpool, const float* __restrict__ Kb,
    const float* __restrict__ Vb, float* __restrict__ O) {
  __shared__ float ss[LMAXS];
  __shared__ float qh[DH];
  __shared__ float red[4];
  __shared__ float part[4][DH];
  int bh = blockIdx.x, b = bh>>3, h = bh&7;
  int tid = threadIdx.x;
  int Lb = c_L[b];
  if (tid < DH) qh[tid] = qpool[h*DH + tid];
  __syncthreads();
  size_t hb = (size_t)c_off[b]*DIM + h*DH;
  for (int k = tid; k < Lb; k += 256) {
    const float4* kp = (const float4*)(Kb + hb + (size_t)k*DIM);
    float a = 0.f;
    #pragma unroll
    for (int dd=0; dd<16; ++dd) {
      float4 kv = kp[dd];
      a += kv.x*qh[dd*4] + kv.y*qh[dd*4+1] + kv.z*qh[dd*4+2] + kv.w*qh[dd*4+3];
    }
    ss[k] = a*0.125f;
  }
  __syncthreads();
  float mx = -1e30f;
  for (int k=tid;k<Lb;k+=256) mx = fmaxf(mx, ss[k]);
  #pragma unroll
  for (int off=32; off; off>>=1) mx = fmaxf(mx, __shfl_xor(mx,off));
  if ((tid&63)==0) red[tid>>6] = mx;
  __syncthreads();
  mx = fmaxf(fmaxf(red[0],red[1]), fmaxf(red[2],red[3]));
  __syncthreads();
  float sum = 0.f;
  for (int k=tid;k<Lb;k+=256) { float p = __expf(ss[k]-mx); ss[k]=p; sum += p; }
  #pragma unroll
  for (int off=32; off; off>>=1) sum += __shfl_xor(sum,off);
  if ((tid&63)==0) red[tid>>6] = sum;
  __syncthreads();
  sum = red[0]+red[1]+red[2]+red[3];
  int d = tid & 63, c = tid >> 6;
  float a = 0.f;
  int kend = min(c*256+256, Lb);
  const float* vb = Vb + hb + d;
  for (int k = c*256; k < kend; ++k) a += ss[k]*vb[(size_t)k*DIM];
  part[c][d] = a;
  __syncthreads();
  if (tid < DH)
    O[(size_t)b*DIM + h*DH + tid] = (part[0][tid]+part[1][tid]+part[2][tid]+part[3][tid]) / sum;
}

// ---- tiny projection Y[8,512] = X[8,512] @ W[512,512]^T ----
__global__ __launch_bounds__(256) void proj512_k(
    const float* __restrict__ X, const float* __restrict__ W, float* __restrict__ Y) {
  __shared__ float xr[DIM];
  int b = blockIdx.x, tid = threadIdx.x;
  for (int i=tid;i<DIM;i+=256) xr[i] = X[(size_t)b*DIM+i];
  __syncthreads();
  for (int n=tid;n<DIM;n+=256) {
    const float4* wr = (const float4*)(W + (size_t)n*DIM);
    float a=0.f;
    for (int k=0;k<DIM/4;++k) { float4 w4 = wr[k]; a += w4.x*xr[k*4]+w4.y*xr[k*4+1]+w4.z*xr[k*4+2]+w4.w*xr[k*4+3]; }
    Y[(size_t)b*DIM+n]=a;
  }
}

// ---- final LN + classifier head ----
__global__ __launch_bounds__(256) void head_out_k(
    const float* __restrict__ X, const float* __restrict__ g,
    const float* __restrict__ W, float* __restrict__ out) {
  __shared__ float xr[DIM];
  __shared__ float red[8];
  int b = blockIdx.x, tid = threadIdx.x;
  float s=0.f, s2=0.f;
  for (int i=tid;i<DIM;i+=256){ float v=X[(size_t)b*DIM+i]; s+=v; s2+=v*v; }
  reduce2_256(s, s2, red);
  float mu=s*(1.f/DIM), rs=rsqrtf(fmaxf(s2*(1.f/DIM)-mu*mu,0.f)+1e-5f);
  for (int i=tid;i<DIM;i+=256) xr[i]=(X[(size_t)b*DIM+i]-mu)*rs*g[i];
  __syncthreads();
  for (int n=tid;n<NC;n+=256) {
    const float4* wr = (const float4*)(W + (size_t)n*DIM);
    float a=0.f;
    for (int k=0;k<DIM/4;++k){ float4 w4=wr[k]; a += w4.x*xr[k*4]+w4.y*xr[k*4+1]+w4.z*xr[k*4+2]+w4.w*xr[k*4+3]; }
    out[(size_t)b*NC+n]=a;
  }
}

extern "C" void kernel_launch(void* const* d_in, const int* in_sizes, int n_in,
                              void* d_out, int out_size, void* d_ws, size_t ws_size,
                              hipStream_t stream) {
  const float* images  = (const float*)d_in[0];
  const float* pe_ln1_w= (const float*)d_in[1];
  const float* pe_ln1_b= (const float*)d_in[2];
  const float* pe_w    = (const float*)d_in[3];
  const float* pe_b    = (const float*)d_in[4];
  const float* pe_ln2_w= (const float*)d_in[5];
  const float* pe_ln2_b= (const float*)d_in[6];
  const float* pos_h   = (const float*)d_in[7];
  const float* pos_w   = (const float*)d_in[8];
  const float* attn_ln = (const float*)d_in[9];
  const float* wq      = (const float*)d_in[10];
  const float* wk      = (const float*)d_in[11];
  const float* wvp     = (const float*)d_in[12];
  const float* qn      = (const float*)d_in[13];
  const float* kn      = (const float*)d_in[14];
  const float* wo      = (const float*)d_in[15];
  const float* ff_ln   = (const float*)d_in[16];
  const float* ff_w1   = (const float*)d_in[17];
  const float* ff_b1   = (const float*)d_in[18];
  const float* ff_w2   = (const float*)d_in[19];
  const float* ff_b2   = (const float*)d_in[20];
  const float* final_ln= (const float*)d_in[21];
  const float* pool_q  = (const float*)d_in[22];
  const float* pool_ln = (const float*)d_in[23];
  const float* pool_wq = (const float*)d_in[24];
  const float* pool_wk = (const float*)d_in[25];
  const float* pool_wv = (const float*)d_in[26];
  const float* pool_qn = (const float*)d_in[27];
  const float* pool_kn = (const float*)d_in[28];
  const float* pool_wo = (const float*)d_in[29];
  const float* head_ln = (const float*)d_in[30];
  const float* head_w  = (const float*)d_in[31];

  const size_t M = MPACK;
  float* ws = (float*)d_ws;
  float* FFH   = ws;                        // M*2048; aliases TOK and ATTO
  float* TOK   = ws;
  float* ATTO  = ws;
  float* T     = ws + M*MLP;
  float* XN    = T    + M*DIM;
  float* Qb    = XN   + M*DIM;
  float* Kbuf  = Qb   + M*DIM;
  float* Vbuf  = Kbuf + M*DIM;
  ushort* Qh   = (ushort*)(Vbuf + M*DIM);   // 64*1024*64 bf16 = 8MB
  ushort* Kh   = Qh + (size_t)64*LMAXS*DH;
  ushort* Vh   = Kh + (size_t)64*LMAXS*DH;
  float* QPOOL = (float*)(Vh + (size_t)64*LMAXS*DH);
  float* POOLO = QPOOL + DIM;
  float* POOLED= POOLO + NB*DIM;
  (void)ws_size; (void)in_sizes; (void)n_in; (void)out_size;

  // ---- patch embed (packed) ----
  pack_ln1_k<<<MPACK, 256, 0, stream>>>(images, pe_ln1_w, pe_ln1_b, TOK);
  gemm_nt<0,0><<<dim3(DIM/128, MPACK/128), 256, 0, stream>>>(TOK, pe_w, pe_b, T, MPACK, DIM, PDIM);
  ln2_pos_k<<<MPACK, 256, 0, stream>>>(T, pe_ln2_w, pe_ln2_b, pos_h, pos_w);

  // ---- transformer layers ----
  for (int l = 0; l < DEPTH; ++l) {
    row_ln_k<<<MPACK, 256, 0, stream>>>(T, attn_ln + l*DIM, XN, DIM);
    gemm_nt<0,0><<<dim3(4, MPACK/128), 256, 0, stream>>>(XN, wq  + (size_t)l*DIM*DIM, nullptr, Qb,   MPACK, DIM, DIM);
    gemm_nt<0,0><<<dim3(4, MPACK/128), 256, 0, stream>>>(XN, wk  + (size_t)l*DIM*DIM, nullptr, Kbuf, MPACK, DIM, DIM);
    gemm_nt<0,0><<<dim3(4, MPACK/128), 256, 0, stream>>>(XN, wvp + (size_t)l*DIM*DIM, nullptr, Vbuf, MPACK, DIM, DIM);
    split_ln_k<<<MVALID, 512, 0, stream>>>(Qb, Kbuf, Vbuf, qn + l*DH, kn + l*DH, Qh, Kh, Vh);
    attn_mfma_k<<<dim3(64, 16), 256, 0, stream>>>(Qh, Kh, Vh, ATTO);
    gemm_nt<0,1><<<dim3(4, MPACK/128), 256, 0, stream>>>(ATTO, wo + (size_t)l*DIM*DIM, nullptr, T, MPACK, DIM, DIM);
    row_ln_k<<<MPACK, 256, 0, stream>>>(T, ff_ln + l*DIM, XN, DIM);
    gemm_nt<1,0><<<dim3(MLP/128, MPACK/128), 256, 0, stream>>>(XN, ff_w1 + (size_t)l*MLP*DIM, ff_b1 + l*MLP, FFH, MPACK, MLP, DIM);
    gemm_nt<0,1><<<dim3(4, MPACK/128), 256, 0, stream>>>(FFH, ff_w2 + (size_t)l*DIM*MLP, ff_b2 + l*DIM, T, MPACK, DIM, MLP);
  }

  // ---- pooling head ----
  row_ln_k<<<MPACK, 256, 0, stream>>>(T, final_ln, XN, DIM);
  pool_prep_k<<<1, 256, 0, stream>>>(pool_q, pool_ln, pool_wq, pool_qn, QPOOL);
  gemm_nt<0,0><<<dim3(4, MPACK/128), 256, 0, stream>>>(XN, pool_wk, nullptr, Kbuf, MPACK, DIM, DIM);
  gemm_nt<0,0><<<dim3(4, MPACK/128), 256, 0, stream>>>(XN, pool_wv, nullptr, Vbuf, MPACK, DIM, DIM);
  head_ln_k<<<MPACK*HEADS/4, 256, 0, stream>>>(Kbuf, pool_kn);
  pool_attn_k<<<NB*HEADS, 256, 0, stream>>>(QPOOL, Kbuf, Vbuf, POOLO);
  proj512_k<<<NB, 256, 0, stream>>>(POOLO, pool_wo, POOLED);
  head_out_k<<<NB, 256, 0, stream>>>(POOLED, head_ln, head_w, (float*)d_out);
}